// Round 6
// baseline (4421.314 us; speedup 1.0000x reference)
//
#include <hip/hip_runtime.h>
#include <hip/hip_bf16.h>

#define HID 64
#define MAXNB 2048  // max buckets (N <= 131072)

// ================= bucket build (bucket = dst >> 6, 64 nodes each) =================

__global__ void bucket_hist_kernel(const int* __restrict__ ei, int* __restrict__ bhist,
                                   int E, int NB) {
    __shared__ int lh[MAXNB];
    int tid = threadIdx.x;
    for (int i = tid; i < NB; i += 256) lh[i] = 0;
    __syncthreads();
    for (long long i = (long long)blockIdx.x * 256 + tid; i < E; i += (long long)gridDim.x * 256)
        atomicAdd(&lh[ei[E + i] >> 6], 1);
    __syncthreads();
    for (int i = tid; i < NB; i += 256) {
        int v = lh[i];
        if (v) atomicAdd(&bhist[i], v);
    }
}

// single-block exclusive scan of bhist[0..NB) -> bptr[0..NB]
__global__ void scan_kernel(const int* __restrict__ deg, int* __restrict__ row_ptr, int N) {
    __shared__ int ssum[256];
    int tid = threadIdx.x;
    int C = (N + 255) / 256;
    int lo = tid * C, hi = min(lo + C, N);
    int s = 0;
    for (int i = lo; i < hi; i++) s += deg[i];
    ssum[tid] = s;
    __syncthreads();
    for (int off = 1; off < 256; off <<= 1) {
        int v = (tid >= off) ? ssum[tid - off] : 0;
        __syncthreads();
        ssum[tid] += v;
        __syncthreads();
    }
    int run = (tid == 0) ? 0 : ssum[tid - 1];
    for (int i = lo; i < hi; i++) {
        row_ptr[i] = run;
        run += deg[i];
    }
    if (hi == N && lo <= N) row_ptr[N] = run;
}

__global__ void copy_int_kernel(const int* __restrict__ src, int* __restrict__ dst, int N) {
    int i = blockIdx.x * blockDim.x + threadIdx.x;
    if (i < N) dst[i] = src[i];
}

// scatter edges into bucket regions, packed (src<<6)|(dst&63)
__global__ void bucket_fill_kernel(const int* __restrict__ ei, int* __restrict__ cursor,
                                   unsigned* __restrict__ ebuf, int E) {
    int e = blockIdx.x * blockDim.x + threadIdx.x;
    if (e >= E) return;
    int s = ei[e];
    int d = ei[E + e];
    int pos = atomicAdd(&cursor[d >> 6], 1);
    ebuf[pos] = ((unsigned)s << 6) | (unsigned)(d & 63);
}

// per-bucket degree histogram -> dinv (deg + 1 self loop)
__global__ void deg_dinv_kernel(const int* __restrict__ bptr, const unsigned* __restrict__ ebuf,
                                float* __restrict__ dinv, int N) {
    __shared__ int ideg[64];
    int tid = threadIdx.x, bkt = blockIdx.x;
    if (tid < 64) ideg[tid] = 0;
    __syncthreads();
    int beg = bptr[bkt], end = bptr[bkt + 1];
    for (int e = beg + tid; e < end; e += 256) atomicAdd(&ideg[ebuf[e] & 63u], 1);
    __syncthreads();
    if (tid < 64) {
        int node = (bkt << 6) + tid;
        if (node < N) dinv[node] = rsqrtf((float)(ideg[tid] + 1));
    }
}

// ================= g = dinv * (in @ W) =================
// 16 nodes per block, 256 threads. In-place safe (block-local rows staged to LDS).
template <int K>
__global__ void gemm_g_kernel(const float* __restrict__ in,
                              const float* __restrict__ W,
                              const float* __restrict__ dinv,
                              float* __restrict__ g, int N) {
    __shared__ float sW[K * HID];
    __shared__ float sIn[16 * K];
    int tid = threadIdx.x;
    for (int idx = tid; idx < K * HID; idx += 256) sW[idx] = W[idx];
    int base = blockIdx.x * 16;
    for (int idx = tid; idx < 16 * K; idx += 256) {
        int r = idx / K, c = idx % K;
        int node = base + r;
        sIn[idx] = (node < N) ? in[(long long)node * K + c] : 0.0f;
    }
    __syncthreads();
    int j = tid & 63;
    int si = tid >> 6;
#pragma unroll
    for (int u = 0; u < 4; u++) {
        int r = si * 4 + u;
        int node = base + r;
        if (node >= N) continue;
        float acc = 0.f;
#pragma unroll
        for (int k = 0; k < K; k++) acc += sIn[r * K + k] * sW[k * HID + j];
        g[(long long)node * HID + j] = dinv[node] * acc;
    }
}

// ================= bucket gather + combine =================
// one WG per bucket; 64x64 fp32 accumulator tile in LDS; lane = feature.
// h[d] = relu(dinv[d]*(sum_in g[s] + g[d]) + b)
__global__ __launch_bounds__(256) void bucket_gather_kernel(
    const int* __restrict__ bptr, const unsigned* __restrict__ ebuf,
    const float* __restrict__ g, const float* __restrict__ dinv,
    const float* __restrict__ bias, float* __restrict__ h, int N) {
    __shared__ float hacc[64 * HID];
    int tid = threadIdx.x;
    int bkt = blockIdx.x;
    for (int i = tid; i < 64 * HID; i += 256) hacc[i] = 0.f;
    __syncthreads();
    int beg = bptr[bkt], end = bptr[bkt + 1];
    int w = tid >> 6, lane = tid & 63;
    for (int blk = beg + w * 64; blk < end; blk += 256) {
        int cnt = min(64, end - blk);
        unsigned ev = (lane < cnt) ? ebuf[blk + lane] : 0u;
        int j = 0;
        for (; j + 4 <= cnt; j += 4) {
            unsigned v0 = __shfl(ev, j);
            unsigned v1 = __shfl(ev, j + 1);
            unsigned v2 = __shfl(ev, j + 2);
            unsigned v3 = __shfl(ev, j + 3);
            float g0 = g[(long long)(v0 >> 6) * HID + lane];
            float g1 = g[(long long)(v1 >> 6) * HID + lane];
            float g2 = g[(long long)(v2 >> 6) * HID + lane];
            float g3 = g[(long long)(v3 >> 6) * HID + lane];
            atomicAdd(&hacc[(v0 & 63u) * HID + lane], g0);
            atomicAdd(&hacc[(v1 & 63u) * HID + lane], g1);
            atomicAdd(&hacc[(v2 & 63u) * HID + lane], g2);
            atomicAdd(&hacc[(v3 & 63u) * HID + lane], g3);
        }
        for (; j < cnt; j++) {
            unsigned v0 = __shfl(ev, j);
            atomicAdd(&hacc[(v0 & 63u) * HID + lane], g[(long long)(v0 >> 6) * HID + lane]);
        }
    }
    __syncthreads();
    // epilogue: each wave writes 16 rows
    for (int r = w * 16; r < w * 16 + 16; r++) {
        int node = (bkt << 6) + r;
        if (node < N) {
            float v = dinv[node] * (hacc[r * HID + lane] + g[(long long)node * HID + lane]) + bias[lane];
            h[(long long)node * HID + lane] = v > 0.f ? v : 0.f;
        }
    }
}

// ================= pooling: segmented reduction (batch is sorted) =================
__global__ void pool_kernel(const float* __restrict__ h, const int* __restrict__ batch,
                            float* __restrict__ sums, float* __restrict__ cnt, int N) {
    int wave = blockIdx.x * 4 + (threadIdx.x >> 6);
    int lane = threadIdx.x & 63;
    int lo = wave * 64;
    if (lo >= N) return;
    int hi = min(lo + 64, N);
    int curb = batch[lo];
    float sum = 0.f;
    int nseg = 0;
    for (int i = lo; i < hi; i++) {
        int b = batch[i];
        if (b != curb) {
            atomicAdd(&sums[curb * HID + lane], sum);
            if (lane == 0) atomicAdd(&cnt[curb], (float)nseg);
            curb = b; sum = 0.f; nseg = 0;
        }
        sum += h[(long long)i * HID + lane];
        nseg++;
    }
    atomicAdd(&sums[curb * HID + lane], sum);
    if (lane == 0) atomicAdd(&cnt[curb], (float)nseg);
}

// ================= final MLP head =================
__global__ void final_kernel(const float* __restrict__ sums, const float* __restrict__ cnt,
                             const float* __restrict__ Wf1, const float* __restrict__ bf1,
                             const float* __restrict__ Wf2, const float* __restrict__ bf2,
                             float* __restrict__ out) {
    __shared__ float sW1[HID * 32];
    __shared__ float sW2[32];
    int tid = threadIdx.x;
    for (int idx = tid; idx < HID * 32; idx += 128) sW1[idx] = Wf1[idx];
    if (tid < 32) sW2[tid] = Wf2[tid];
    __syncthreads();
    int b = tid;
    float pooled[HID];
    float c = fmaxf(cnt[b], 1.0f);
#pragma unroll
    for (int j = 0; j < HID; j++) pooled[j] = sums[b * HID + j] / c;
    float o = bf2[0];
#pragma unroll 4
    for (int hd = 0; hd < 32; hd++) {
        float z = bf1[hd];
#pragma unroll
        for (int j = 0; j < HID; j++) z += pooled[j] * sW1[j * 32 + hd];
        z = fmaxf(z, 0.f);
        o += z * sW2[hd];
    }
    out[b] = o;
}

extern "C" void kernel_launch(void* const* d_in, const int* in_sizes, int n_in,
                              void* d_out, int out_size, void* d_ws, size_t ws_size,
                              hipStream_t stream) {
    const float* x     = (const float*)d_in[0];
    const int*   ei    = (const int*)d_in[1];
    const int*   batch = (const int*)d_in[3];
    const float* W1  = (const float*)d_in[4];
    const float* b1  = (const float*)d_in[5];
    const float* W2  = (const float*)d_in[6];
    const float* b2  = (const float*)d_in[7];
    const float* W3  = (const float*)d_in[8];
    const float* b3  = (const float*)d_in[9];
    const float* Wf1 = (const float*)d_in[10];
    const float* bf1 = (const float*)d_in[11];
    const float* Wf2 = (const float*)d_in[12];
    const float* bf2 = (const float*)d_in[13];
    float* out = (float*)d_out;

    const int N  = in_sizes[0] / 16;   // 100000
    const int E  = in_sizes[1] / 2;    // 3200000
    const int NB = (N + 63) / 64;      // 1563 buckets

    // workspace layout (~65 MB)
    char* ws = (char*)d_ws;
    size_t o = 0;
    float*    dinv   = (float*)(ws + o);    o += ((size_t)N * 4 + 4095) / 4096 * 4096;
    int*      bptr   = (int*)(ws + o);      o += ((size_t)(NB + 1) * 4 + 4095) / 4096 * 4096;
    int*      bhist  = (int*)(ws + o);      o += ((size_t)NB * 4 + 4095) / 4096 * 4096;
    int*      cursor = (int*)(ws + o);      o += ((size_t)NB * 4 + 4095) / 4096 * 4096;
    unsigned* ebuf   = (unsigned*)(ws + o); o += (size_t)E * 4;        // 12.8 MB
    float*    A      = (float*)(ws + o);    o += (size_t)N * HID * 4;  // 25.6 MB
    float*    B      = (float*)(ws + o);    o += (size_t)N * HID * 4;  // 25.6 MB
    float*    sums   = (float*)(ws + o);    o += 128 * HID * 4;
    float*    cnt    = (float*)(ws + o);    o += 128 * 4;
    (void)ws_size;

    const int T = 256;
    const int gE  = (E + T - 1) / T;
    const int gGm = (N + 15) / 16;
    const int gPool = ((N + 63) / 64 + 3) / 4;
    const int gNB = (NB + T - 1) / T;

    // ---- bucket-CSR build ----
    hipMemsetAsync(bhist, 0, (size_t)NB * 4, stream);
    bucket_hist_kernel<<<256, T, 0, stream>>>(ei, bhist, E, NB);
    scan_kernel<<<1, 256, 0, stream>>>(bhist, bptr, NB);
    copy_int_kernel<<<gNB, T, 0, stream>>>(bptr, cursor, NB);
    bucket_fill_kernel<<<gE, T, 0, stream>>>(ei, cursor, ebuf, E);
    deg_dinv_kernel<<<NB, T, 0, stream>>>(bptr, ebuf, dinv, N);

    // ---- layer 1: x(K=16) -> A -> gather -> B ----
    gemm_g_kernel<16><<<gGm, T, 0, stream>>>(x, W1, dinv, A, N);
    bucket_gather_kernel<<<NB, T, 0, stream>>>(bptr, ebuf, A, dinv, b1, B, N);

    // ---- layer 2: B -> B (in-place gemm) -> gather -> A ----
    gemm_g_kernel<64><<<gGm, T, 0, stream>>>(B, W2, dinv, B, N);
    bucket_gather_kernel<<<NB, T, 0, stream>>>(bptr, ebuf, B, dinv, b2, A, N);

    // ---- layer 3: A -> A -> gather -> B ----
    gemm_g_kernel<64><<<gGm, T, 0, stream>>>(A, W3, dinv, A, N);
    bucket_gather_kernel<<<NB, T, 0, stream>>>(bptr, ebuf, A, dinv, b3, B, N);

    // ---- pool + head ----
    hipMemsetAsync(sums, 0, (128 * HID + 128) * 4, stream);
    pool_kernel<<<gPool, T, 0, stream>>>(B, batch, sums, cnt, N);
    final_kernel<<<1, 128, 0, stream>>>(sums, cnt, Wf1, bf1, Wf2, bf2, out);
}

// Round 7
// 1011.260 us; speedup vs baseline: 4.3721x; 4.3721x over previous
//
#include <hip/hip_runtime.h>
#include <hip/hip_bf16.h>

#define HID 64
#define MAXNB 2048  // max buckets (N <= 131072)

__device__ __forceinline__ float bf2f(unsigned short u) {
    return __uint_as_float(((unsigned)u) << 16);
}
__device__ __forceinline__ unsigned short f2bf(float f) {
    __hip_bfloat16 b = __float2bfloat16(f);  // RNE
    return *(unsigned short*)&b;
}

// ================= bucket build (bucket = dst >> 6, 64 nodes each) =================

__global__ void bucket_hist_kernel(const int* __restrict__ ei, int* __restrict__ bhist,
                                   int E, int NB) {
    __shared__ int lh[MAXNB];
    int tid = threadIdx.x;
    for (int i = tid; i < NB; i += 256) lh[i] = 0;
    __syncthreads();
    for (long long i = (long long)blockIdx.x * 256 + tid; i < E; i += (long long)gridDim.x * 256)
        atomicAdd(&lh[ei[E + i] >> 6], 1);
    __syncthreads();
    for (int i = tid; i < NB; i += 256) {
        int v = lh[i];
        if (v) atomicAdd(&bhist[i], v);
    }
}

// single-block exclusive scan of bhist[0..NB) -> bptr[0..NB]
__global__ void scan_kernel(const int* __restrict__ deg, int* __restrict__ row_ptr, int N) {
    __shared__ int ssum[256];
    int tid = threadIdx.x;
    int C = (N + 255) / 256;
    int lo = tid * C, hi = min(lo + C, N);
    int s = 0;
    for (int i = lo; i < hi; i++) s += deg[i];
    ssum[tid] = s;
    __syncthreads();
    for (int off = 1; off < 256; off <<= 1) {
        int v = (tid >= off) ? ssum[tid - off] : 0;
        __syncthreads();
        ssum[tid] += v;
        __syncthreads();
    }
    int run = (tid == 0) ? 0 : ssum[tid - 1];
    for (int i = lo; i < hi; i++) {
        row_ptr[i] = run;
        run += deg[i];
    }
    if (hi == N && lo <= N) row_ptr[N] = run;
}

__global__ void copy_int_kernel(const int* __restrict__ src, int* __restrict__ dst, int N) {
    int i = blockIdx.x * blockDim.x + threadIdx.x;
    if (i < N) dst[i] = src[i];
}

// scatter edges into bucket regions, packed (src<<6)|(dst&63)
__global__ void bucket_fill_kernel(const int* __restrict__ ei, int* __restrict__ cursor,
                                   unsigned* __restrict__ ebuf, int E) {
    int e = blockIdx.x * blockDim.x + threadIdx.x;
    if (e >= E) return;
    int s = ei[e];
    int d = ei[E + e];
    int pos = atomicAdd(&cursor[d >> 6], 1);
    ebuf[pos] = ((unsigned)s << 6) | (unsigned)(d & 63);
}

// per-bucket counting sort: ebuf bucket region -> node-sorted col; also row_ptr + dinv.
__global__ __launch_bounds__(256) void node_csr_kernel(
    const int* __restrict__ bptr, const unsigned* __restrict__ ebuf,
    int* __restrict__ row_ptr, int* __restrict__ col, float* __restrict__ dinv,
    int N, int NB) {
    __shared__ int lcnt[64];
    __shared__ int loff[64];
    __shared__ int lcur[64];
    int bkt = blockIdx.x, tid = threadIdx.x;
    int beg = bptr[bkt], end = bptr[bkt + 1];
    if (tid < 64) lcnt[tid] = 0;
    __syncthreads();
    for (int e = beg + tid; e < end; e += 256) atomicAdd(&lcnt[ebuf[e] & 63u], 1);
    __syncthreads();
    if (tid == 0) {
        int run = beg;
        for (int i = 0; i < 64; i++) { loff[i] = run; lcur[i] = run; run += lcnt[i]; }
    }
    __syncthreads();
    if (tid < 64) {
        int node = (bkt << 6) + tid;
        if (node < N) {
            row_ptr[node] = loff[tid];
            dinv[node] = rsqrtf((float)(lcnt[tid] + 1));  // +1 self loop
        }
    }
    if (tid == 0 && bkt == NB - 1) row_ptr[N] = end;
    for (int e = beg + tid; e < end; e += 256) {
        unsigned ev = ebuf[e];
        int pos = atomicAdd(&lcur[ev & 63u], 1);
        col[pos] = (int)(ev >> 6);
    }
}

// ================= g = bf16(dinv * (in @ W)) =================
// 16 nodes per block, 256 threads. In-place safe (block-local rows staged to LDS).
template <typename Tin, int K>
__global__ void gemm_g_kernel(const Tin* __restrict__ in,
                              const float* __restrict__ W,
                              const float* __restrict__ dinv,
                              unsigned short* __restrict__ g, int N) {
    __shared__ float sW[K * HID];
    __shared__ float sIn[16 * K];
    int tid = threadIdx.x;
    for (int idx = tid; idx < K * HID; idx += 256) sW[idx] = W[idx];
    int base = blockIdx.x * 16;
    for (int idx = tid; idx < 16 * K; idx += 256) {
        int r = idx / K, c = idx % K;
        int node = base + r;
        float v = 0.f;
        if (node < N) {
            Tin t = in[(long long)node * K + c];
            if constexpr (sizeof(Tin) == 2) v = bf2f((unsigned short)t);
            else v = (float)t;
        }
        sIn[idx] = v;
    }
    __syncthreads();
    int j = tid & 63;
    int si = tid >> 6;
#pragma unroll
    for (int u = 0; u < 4; u++) {
        int r = si * 4 + u;
        int node = base + r;
        if (node >= N) continue;
        float acc = 0.f;
#pragma unroll
        for (int k = 0; k < K; k++) acc += sIn[r * K + k] * sW[k * HID + j];
        g[(long long)node * HID + j] = f2bf(dinv[node] * acc);
    }
}

// ================= gather + combine: h[d] = relu(dinv[d]*(g[d] + sum_in g[s]) + b) ==========
// one wave per dst node, lane = feature; ILP-4 independent row loads.
__global__ __launch_bounds__(256) void gather_kernel(
    const int* __restrict__ row_ptr, const int* __restrict__ col,
    const unsigned short* __restrict__ g, const float* __restrict__ dinv,
    const float* __restrict__ bias, unsigned short* __restrict__ h, int N) {
    int node = blockIdx.x * 4 + (threadIdx.x >> 6);
    int lane = threadIdx.x & 63;
    if (node >= N) return;
    int beg = row_ptr[node], end = row_ptr[node + 1];
    float sum = bf2f(g[(long long)node * HID + lane]);  // self loop
    for (int e0 = beg; e0 < end; e0 += 64) {
        int myE = e0 + lane;
        int cs = (myE < end) ? col[myE] : 0;
        int cnt = min(64, end - e0);
        int j = 0;
        for (; j + 4 <= cnt; j += 4) {
            int s0 = __shfl(cs, j);
            int s1 = __shfl(cs, j + 1);
            int s2 = __shfl(cs, j + 2);
            int s3 = __shfl(cs, j + 3);
            float f0 = bf2f(g[(long long)s0 * HID + lane]);
            float f1 = bf2f(g[(long long)s1 * HID + lane]);
            float f2 = bf2f(g[(long long)s2 * HID + lane]);
            float f3 = bf2f(g[(long long)s3 * HID + lane]);
            sum += (f0 + f1) + (f2 + f3);
        }
        for (; j < cnt; j++) {
            int s = __shfl(cs, j);
            sum += bf2f(g[(long long)s * HID + lane]);
        }
    }
    float v = dinv[node] * sum + bias[lane];
    h[(long long)node * HID + lane] = f2bf(v > 0.f ? v : 0.f);
}

// ================= pooling: segmented reduction (batch is sorted) =================
__global__ void pool_kernel(const unsigned short* __restrict__ h, const int* __restrict__ batch,
                            float* __restrict__ sums, float* __restrict__ cnt, int N) {
    int wave = blockIdx.x * 4 + (threadIdx.x >> 6);
    int lane = threadIdx.x & 63;
    int lo = wave * 64;
    if (lo >= N) return;
    int hi = min(lo + 64, N);
    int curb = batch[lo];
    float sum = 0.f;
    int nseg = 0;
    for (int i = lo; i < hi; i++) {
        int b = batch[i];
        if (b != curb) {
            atomicAdd(&sums[curb * HID + lane], sum);
            if (lane == 0) atomicAdd(&cnt[curb], (float)nseg);
            curb = b; sum = 0.f; nseg = 0;
        }
        sum += bf2f(h[(long long)i * HID + lane]);
        nseg++;
    }
    atomicAdd(&sums[curb * HID + lane], sum);
    if (lane == 0) atomicAdd(&cnt[curb], (float)nseg);
}

// ================= final MLP head =================
__global__ void final_kernel(const float* __restrict__ sums, const float* __restrict__ cnt,
                             const float* __restrict__ Wf1, const float* __restrict__ bf1,
                             const float* __restrict__ Wf2, const float* __restrict__ bf2,
                             float* __restrict__ out) {
    __shared__ float sW1[HID * 32];
    __shared__ float sW2[32];
    int tid = threadIdx.x;
    for (int idx = tid; idx < HID * 32; idx += 128) sW1[idx] = Wf1[idx];
    if (tid < 32) sW2[tid] = Wf2[tid];
    __syncthreads();
    int b = tid;
    float pooled[HID];
    float c = fmaxf(cnt[b], 1.0f);
#pragma unroll
    for (int j = 0; j < HID; j++) pooled[j] = sums[b * HID + j] / c;
    float o = bf2[0];
#pragma unroll 4
    for (int hd = 0; hd < 32; hd++) {
        float z = bf1[hd];
#pragma unroll
        for (int j = 0; j < HID; j++) z += pooled[j] * sW1[j * 32 + hd];
        z = fmaxf(z, 0.f);
        o += z * sW2[hd];
    }
    out[b] = o;
}

extern "C" void kernel_launch(void* const* d_in, const int* in_sizes, int n_in,
                              void* d_out, int out_size, void* d_ws, size_t ws_size,
                              hipStream_t stream) {
    const float* x     = (const float*)d_in[0];
    const int*   ei    = (const int*)d_in[1];
    const int*   batch = (const int*)d_in[3];
    const float* W1  = (const float*)d_in[4];
    const float* b1  = (const float*)d_in[5];
    const float* W2  = (const float*)d_in[6];
    const float* b2  = (const float*)d_in[7];
    const float* W3  = (const float*)d_in[8];
    const float* b3  = (const float*)d_in[9];
    const float* Wf1 = (const float*)d_in[10];
    const float* bf1 = (const float*)d_in[11];
    const float* Wf2 = (const float*)d_in[12];
    const float* bf2 = (const float*)d_in[13];
    float* out = (float*)d_out;

    const int N  = in_sizes[0] / 16;   // 100000
    const int E  = in_sizes[1] / 2;    // 3200000
    const int NB = (N + 63) / 64;      // 1563 buckets

    // workspace layout (~53 MB)
    char* ws = (char*)d_ws;
    size_t o = 0;
    float*          dinv    = (float*)(ws + o);          o += ((size_t)N * 4 + 4095) / 4096 * 4096;
    int*            row_ptr = (int*)(ws + o);            o += ((size_t)(N + 1) * 4 + 4095) / 4096 * 4096;
    int*            bptr    = (int*)(ws + o);            o += ((size_t)(NB + 1) * 4 + 4095) / 4096 * 4096;
    int*            bhist   = (int*)(ws + o);            o += ((size_t)NB * 4 + 4095) / 4096 * 4096;
    int*            cursor  = (int*)(ws + o);            o += ((size_t)NB * 4 + 4095) / 4096 * 4096;
    unsigned*       ebuf    = (unsigned*)(ws + o);       o += (size_t)E * 4;        // 12.8 MB
    int*            col     = (int*)(ws + o);            o += (size_t)E * 4;        // 12.8 MB
    unsigned short* A       = (unsigned short*)(ws + o); o += (size_t)N * HID * 2;  // 12.8 MB
    unsigned short* B       = (unsigned short*)(ws + o); o += (size_t)N * HID * 2;  // 12.8 MB
    float*          sums    = (float*)(ws + o);          o += 128 * HID * 4;
    float*          cnt     = (float*)(ws + o);          o += 128 * 4;
    (void)ws_size;

    const int T = 256;
    const int gE  = (E + T - 1) / T;
    const int gGm = (N + 15) / 16;
    const int gGa = (N + 3) / 4;
    const int gPool = ((N + 63) / 64 + 3) / 4;
    const int gNB = (NB + T - 1) / T;

    // ---- CSR build: bucket fill, then per-bucket counting sort ----
    hipMemsetAsync(bhist, 0, (size_t)NB * 4, stream);
    bucket_hist_kernel<<<256, T, 0, stream>>>(ei, bhist, E, NB);
    scan_kernel<<<1, 256, 0, stream>>>(bhist, bptr, NB);
    copy_int_kernel<<<gNB, T, 0, stream>>>(bptr, cursor, NB);
    bucket_fill_kernel<<<gE, T, 0, stream>>>(ei, cursor, ebuf, E);
    node_csr_kernel<<<NB, T, 0, stream>>>(bptr, ebuf, row_ptr, col, dinv, N, NB);

    // ---- layer 1: x(f32, K=16) -> A -> gather -> B ----
    gemm_g_kernel<float, 16><<<gGm, T, 0, stream>>>(x, W1, dinv, A, N);
    gather_kernel<<<gGa, T, 0, stream>>>(row_ptr, col, A, dinv, b1, B, N);

    // ---- layer 2: B -> B (in-place gemm) -> gather -> A ----
    gemm_g_kernel<unsigned short, 64><<<gGm, T, 0, stream>>>(B, W2, dinv, B, N);
    gather_kernel<<<gGa, T, 0, stream>>>(row_ptr, col, B, dinv, b2, A, N);

    // ---- layer 3: A -> A -> gather -> B ----
    gemm_g_kernel<unsigned short, 64><<<gGm, T, 0, stream>>>(A, W3, dinv, A, N);
    gather_kernel<<<gGa, T, 0, stream>>>(row_ptr, col, A, dinv, b3, B, N);

    // ---- pool + head ----
    hipMemsetAsync(sums, 0, (128 * HID + 128) * 4, stream);
    pool_kernel<<<gPool, T, 0, stream>>>(B, batch, sums, cnt, N);
    final_kernel<<<1, 128, 0, stream>>>(sums, cnt, Wf1, bf1, Wf2, bf2, out);
}

// Round 8
// 974.669 us; speedup vs baseline: 4.5362x; 1.0375x over previous
//
#include <hip/hip_runtime.h>
#include <hip/hip_bf16.h>

#define HID 64
#define MAXNB 2048   // max buckets (N <= 131072)
#define NBLK 128     // radix partition blocks (power of 2)

__device__ __forceinline__ float bf2f(unsigned short u) {
    return __uint_as_float(((unsigned)u) << 16);
}
__device__ __forceinline__ unsigned short f2bf(float f) {
    __hip_bfloat16 b = __float2bfloat16(f);  // RNE
    return *(unsigned short*)&b;
}

// ================= radix partition by bucket (bucket = dst >> 6) =================

// pass 1: per-block LDS histogram of its chunk -> H[blk][NB] (block-major, coalesced)
__global__ __launch_bounds__(256) void radix_hist_kernel(
    const int* __restrict__ ei, int* __restrict__ H, int E, int NB, int C) {
    __shared__ int lh[MAXNB];
    int blk = blockIdx.x, tid = threadIdx.x;
    for (int i = tid; i < NB; i += 256) lh[i] = 0;
    __syncthreads();
    int lo = blk * C, hi = min(lo + C, E);
    for (int e = lo + tid; e < hi; e += 256) atomicAdd(&lh[ei[E + e] >> 6], 1);
    __syncthreads();
    for (int i = tid; i < NB; i += 256) H[blk * NB + i] = lh[i];
}

// pass 2: single-block exclusive scan over bucket-major (b,i) order.
// OFF[i*NB+b] = start offset for (block i, bucket b); bptr[b] = bucket start; bptr[NB]=E.
__global__ __launch_bounds__(256) void radix_scan_kernel(
    const int* __restrict__ H, int* __restrict__ OFF, int* __restrict__ bptr, int NB) {
    __shared__ int ssum[256];
    int tid = threadIdx.x;
    int total = NB * NBLK;
    int C = (total + 255) / 256;
    int lo = tid * C, hi = min(lo + C, total);
    int s = 0;
    for (int idx = lo; idx < hi; idx++) {
        int b = idx >> 7, i = idx & (NBLK - 1);   // NBLK == 128
        s += H[i * NB + b];
    }
    ssum[tid] = s;
    __syncthreads();
    for (int off = 1; off < 256; off <<= 1) {
        int v = (tid >= off) ? ssum[tid - off] : 0;
        __syncthreads();
        ssum[tid] += v;
        __syncthreads();
    }
    int run = (tid == 0) ? 0 : ssum[tid - 1];
    for (int idx = lo; idx < hi; idx++) {
        int b = idx >> 7, i = idx & (NBLK - 1);
        if (i == 0) bptr[b] = run;
        OFF[i * NB + b] = run;
        run += H[i * NB + b];
    }
    if (hi == total) bptr[NB] = run;  // == E (safe if multiple threads write)
}

// pass 3: scatter edges; ranks via block-private LDS cursors -> no global atomics,
// each (block,bucket) output region is written by exactly one block.
__global__ __launch_bounds__(256) void radix_fill_kernel(
    const int* __restrict__ ei, const int* __restrict__ OFF,
    unsigned* __restrict__ ebuf, int E, int NB, int C) {
    __shared__ int lcur[MAXNB];
    int blk = blockIdx.x, tid = threadIdx.x;
    for (int i = tid; i < NB; i += 256) lcur[i] = OFF[blk * NB + i];
    __syncthreads();
    int lo = blk * C, hi = min(lo + C, E);
    for (int e = lo + tid; e < hi; e += 256) {
        int s = ei[e];
        int d = ei[E + e];
        int pos = atomicAdd(&lcur[d >> 6], 1);
        ebuf[pos] = ((unsigned)s << 6) | (unsigned)(d & 63);
    }
}

// per-bucket counting sort: ebuf bucket region -> node-sorted col; also row_ptr + dinv.
__global__ __launch_bounds__(256) void node_csr_kernel(
    const int* __restrict__ bptr, const unsigned* __restrict__ ebuf,
    int* __restrict__ row_ptr, int* __restrict__ col, float* __restrict__ dinv,
    int N, int NB) {
    __shared__ int lcnt[64];
    __shared__ int loff[64];
    __shared__ int lcur[64];
    int bkt = blockIdx.x, tid = threadIdx.x;
    int beg = bptr[bkt], end = bptr[bkt + 1];
    if (tid < 64) lcnt[tid] = 0;
    __syncthreads();
    for (int e = beg + tid; e < end; e += 256) atomicAdd(&lcnt[ebuf[e] & 63u], 1);
    __syncthreads();
    if (tid == 0) {
        int run = beg;
        for (int i = 0; i < 64; i++) { loff[i] = run; lcur[i] = run; run += lcnt[i]; }
    }
    __syncthreads();
    if (tid < 64) {
        int node = (bkt << 6) + tid;
        if (node < N) {
            row_ptr[node] = loff[tid];
            dinv[node] = rsqrtf((float)(lcnt[tid] + 1));  // +1 self loop
        }
    }
    if (tid == 0 && bkt == NB - 1) row_ptr[N] = end;
    for (int e = beg + tid; e < end; e += 256) {
        unsigned ev = ebuf[e];
        int pos = atomicAdd(&lcur[ev & 63u], 1);
        col[pos] = (int)(ev >> 6);
    }
}

// ================= g = bf16(dinv * (in @ W)) =================
// 16 nodes per block, 256 threads. In-place safe (block-local rows staged to LDS).
template <typename Tin, int K>
__global__ void gemm_g_kernel(const Tin* __restrict__ in,
                              const float* __restrict__ W,
                              const float* __restrict__ dinv,
                              unsigned short* __restrict__ g, int N) {
    __shared__ float sW[K * HID];
    __shared__ float sIn[16 * K];
    int tid = threadIdx.x;
    for (int idx = tid; idx < K * HID; idx += 256) sW[idx] = W[idx];
    int base = blockIdx.x * 16;
    for (int idx = tid; idx < 16 * K; idx += 256) {
        int r = idx / K, c = idx % K;
        int node = base + r;
        float v = 0.f;
        if (node < N) {
            Tin t = in[(long long)node * K + c];
            if constexpr (sizeof(Tin) == 2) v = bf2f((unsigned short)t);
            else v = (float)t;
        }
        sIn[idx] = v;
    }
    __syncthreads();
    int j = tid & 63;
    int si = tid >> 6;
#pragma unroll
    for (int u = 0; u < 4; u++) {
        int r = si * 4 + u;
        int node = base + r;
        if (node >= N) continue;
        float acc = 0.f;
#pragma unroll
        for (int k = 0; k < K; k++) acc += sIn[r * K + k] * sW[k * HID + j];
        g[(long long)node * HID + j] = f2bf(dinv[node] * acc);
    }
}

// ================= gather + combine: h[d] = relu(dinv[d]*(g[d] + sum_in g[s]) + b) ==========
// one wave per dst node, lane = feature; ILP-4 independent row loads.
__global__ __launch_bounds__(256) void gather_kernel(
    const int* __restrict__ row_ptr, const int* __restrict__ col,
    const unsigned short* __restrict__ g, const float* __restrict__ dinv,
    const float* __restrict__ bias, unsigned short* __restrict__ h, int N) {
    int node = blockIdx.x * 4 + (threadIdx.x >> 6);
    int lane = threadIdx.x & 63;
    if (node >= N) return;
    int beg = row_ptr[node], end = row_ptr[node + 1];
    float sum = bf2f(g[(long long)node * HID + lane]);  // self loop
    for (int e0 = beg; e0 < end; e0 += 64) {
        int myE = e0 + lane;
        int cs = (myE < end) ? col[myE] : 0;
        int cnt = min(64, end - e0);
        int j = 0;
        for (; j + 4 <= cnt; j += 4) {
            int s0 = __shfl(cs, j);
            int s1 = __shfl(cs, j + 1);
            int s2 = __shfl(cs, j + 2);
            int s3 = __shfl(cs, j + 3);
            float f0 = bf2f(g[(long long)s0 * HID + lane]);
            float f1 = bf2f(g[(long long)s1 * HID + lane]);
            float f2 = bf2f(g[(long long)s2 * HID + lane]);
            float f3 = bf2f(g[(long long)s3 * HID + lane]);
            sum += (f0 + f1) + (f2 + f3);
        }
        for (; j < cnt; j++) {
            int s = __shfl(cs, j);
            sum += bf2f(g[(long long)s * HID + lane]);
        }
    }
    float v = dinv[node] * sum + bias[lane];
    h[(long long)node * HID + lane] = f2bf(v > 0.f ? v : 0.f);
}

// ================= pooling: segmented reduction (batch is sorted) =================
__global__ void pool_kernel(const unsigned short* __restrict__ h, const int* __restrict__ batch,
                            float* __restrict__ sums, float* __restrict__ cnt, int N) {
    int wave = blockIdx.x * 4 + (threadIdx.x >> 6);
    int lane = threadIdx.x & 63;
    int lo = wave * 64;
    if (lo >= N) return;
    int hi = min(lo + 64, N);
    int curb = batch[lo];
    float sum = 0.f;
    int nseg = 0;
    for (int i = lo; i < hi; i++) {
        int b = batch[i];
        if (b != curb) {
            atomicAdd(&sums[curb * HID + lane], sum);
            if (lane == 0) atomicAdd(&cnt[curb], (float)nseg);
            curb = b; sum = 0.f; nseg = 0;
        }
        sum += bf2f(h[(long long)i * HID + lane]);
        nseg++;
    }
    atomicAdd(&sums[curb * HID + lane], sum);
    if (lane == 0) atomicAdd(&cnt[curb], (float)nseg);
}

// ================= final MLP head =================
__global__ void final_kernel(const float* __restrict__ sums, const float* __restrict__ cnt,
                             const float* __restrict__ Wf1, const float* __restrict__ bf1,
                             const float* __restrict__ Wf2, const float* __restrict__ bf2,
                             float* __restrict__ out) {
    __shared__ float sW1[HID * 32];
    __shared__ float sW2[32];
    int tid = threadIdx.x;
    for (int idx = tid; idx < HID * 32; idx += 128) sW1[idx] = Wf1[idx];
    if (tid < 32) sW2[tid] = Wf2[tid];
    __syncthreads();
    int b = tid;
    float pooled[HID];
    float c = fmaxf(cnt[b], 1.0f);
#pragma unroll
    for (int j = 0; j < HID; j++) pooled[j] = sums[b * HID + j] / c;
    float o = bf2[0];
#pragma unroll 4
    for (int hd = 0; hd < 32; hd++) {
        float z = bf1[hd];
#pragma unroll
        for (int j = 0; j < HID; j++) z += pooled[j] * sW1[j * 32 + hd];
        z = fmaxf(z, 0.f);
        o += z * sW2[hd];
    }
    out[b] = o;
}

extern "C" void kernel_launch(void* const* d_in, const int* in_sizes, int n_in,
                              void* d_out, int out_size, void* d_ws, size_t ws_size,
                              hipStream_t stream) {
    const float* x     = (const float*)d_in[0];
    const int*   ei    = (const int*)d_in[1];
    const int*   batch = (const int*)d_in[3];
    const float* W1  = (const float*)d_in[4];
    const float* b1  = (const float*)d_in[5];
    const float* W2  = (const float*)d_in[6];
    const float* b2  = (const float*)d_in[7];
    const float* W3  = (const float*)d_in[8];
    const float* b3  = (const float*)d_in[9];
    const float* Wf1 = (const float*)d_in[10];
    const float* bf1 = (const float*)d_in[11];
    const float* Wf2 = (const float*)d_in[12];
    const float* bf2 = (const float*)d_in[13];
    float* out = (float*)d_out;

    const int N  = in_sizes[0] / 16;   // 100000
    const int E  = in_sizes[1] / 2;    // 3200000
    const int NB = (N + 63) / 64;      // 1563 buckets

    // workspace layout (~55 MB)
    char* ws = (char*)d_ws;
    size_t o = 0;
    float*          dinv    = (float*)(ws + o);          o += ((size_t)N * 4 + 4095) / 4096 * 4096;
    int*            row_ptr = (int*)(ws + o);            o += ((size_t)(N + 1) * 4 + 4095) / 4096 * 4096;
    int*            bptr    = (int*)(ws + o);            o += ((size_t)(NB + 1) * 4 + 4095) / 4096 * 4096;
    int*            H       = (int*)(ws + o);            o += ((size_t)NBLK * NB * 4 + 4095) / 4096 * 4096;  // 0.8 MB
    int*            OFF     = (int*)(ws + o);            o += ((size_t)NBLK * NB * 4 + 4095) / 4096 * 4096;  // 0.8 MB
    unsigned*       ebuf    = (unsigned*)(ws + o);       o += (size_t)E * 4;        // 12.8 MB
    int*            col     = (int*)(ws + o);            o += (size_t)E * 4;        // 12.8 MB
    unsigned short* A       = (unsigned short*)(ws + o); o += (size_t)N * HID * 2;  // 12.8 MB
    unsigned short* B       = (unsigned short*)(ws + o); o += (size_t)N * HID * 2;  // 12.8 MB
    float*          sums    = (float*)(ws + o);          o += 128 * HID * 4;
    float*          cnt     = (float*)(ws + o);          o += 128 * 4;
    (void)ws_size;

    const int T = 256;
    const int Cchunk = (E + NBLK - 1) / NBLK;
    const int gGm = (N + 15) / 16;
    const int gGa = (N + 3) / 4;
    const int gPool = ((N + 63) / 64 + 3) / 4;

    // ---- CSR build: block-local radix partition, then per-bucket counting sort ----
    radix_hist_kernel<<<NBLK, T, 0, stream>>>(ei, H, E, NB, Cchunk);
    radix_scan_kernel<<<1, T, 0, stream>>>(H, OFF, bptr, NB);
    radix_fill_kernel<<<NBLK, T, 0, stream>>>(ei, OFF, ebuf, E, NB, Cchunk);
    node_csr_kernel<<<NB, T, 0, stream>>>(bptr, ebuf, row_ptr, col, dinv, N, NB);

    // ---- layer 1: x(f32, K=16) -> A -> gather -> B ----
    gemm_g_kernel<float, 16><<<gGm, T, 0, stream>>>(x, W1, dinv, A, N);
    gather_kernel<<<gGa, T, 0, stream>>>(row_ptr, col, A, dinv, b1, B, N);

    // ---- layer 2: B -> B (in-place gemm) -> gather -> A ----
    gemm_g_kernel<unsigned short, 64><<<gGm, T, 0, stream>>>(B, W2, dinv, B, N);
    gather_kernel<<<gGa, T, 0, stream>>>(row_ptr, col, B, dinv, b2, A, N);

    // ---- layer 3: A -> A -> gather -> B ----
    gemm_g_kernel<unsigned short, 64><<<gGm, T, 0, stream>>>(A, W3, dinv, A, N);
    gather_kernel<<<gGa, T, 0, stream>>>(row_ptr, col, A, dinv, b3, B, N);

    // ---- pool + head ----
    hipMemsetAsync(sums, 0, (128 * HID + 128) * 4, stream);
    pool_kernel<<<gPool, T, 0, stream>>>(B, batch, sums, cnt, N);
    final_kernel<<<1, 128, 0, stream>>>(sums, cnt, Wf1, bf1, Wf2, bf2, out);
}

// Round 9
// 626.900 us; speedup vs baseline: 7.0527x; 1.5547x over previous
//
#include <hip/hip_runtime.h>
#include <hip/hip_bf16.h>

#define HID 64
#define MAXNB 2048   // max buckets (N <= 131072)
#define NBLK 128     // radix partition blocks

__device__ __forceinline__ float bf2f(unsigned short u) {
    return __uint_as_float(((unsigned)u) << 16);
}
__device__ __forceinline__ unsigned short f2bf(float f) {
    __hip_bfloat16 b = __float2bfloat16(f);  // RNE
    return *(unsigned short*)&b;
}

// ================= radix partition by bucket (bucket = dst >> 6) =================

// pass 1: per-block LDS histogram of its chunk -> H[blk][NB] + global bucket totals
__global__ __launch_bounds__(256) void radix_hist_kernel(
    const int* __restrict__ ei, int* __restrict__ H, int* __restrict__ bhist,
    int E, int NB, int C) {
    __shared__ int lh[MAXNB];
    int blk = blockIdx.x, tid = threadIdx.x;
    for (int i = tid; i < NB; i += 256) lh[i] = 0;
    __syncthreads();
    int lo = blk * C, hi = min(lo + C, E);
    for (int e = lo + tid; e < hi; e += 256) atomicAdd(&lh[ei[E + e] >> 6], 1);
    __syncthreads();
    for (int i = tid; i < NB; i += 256) {
        int v = lh[i];
        H[blk * NB + i] = v;
        if (v) atomicAdd(&bhist[i], v);
    }
}

// pass 2: single-block exclusive scan over NB bucket totals -> bptr + cursor init
__global__ __launch_bounds__(256) void scan_kernel(
    const int* __restrict__ bhist, int* __restrict__ bptr, int* __restrict__ gcur, int NB) {
    __shared__ int ssum[256];
    int tid = threadIdx.x;
    int C = (NB + 255) / 256;
    int lo = tid * C, hi = min(lo + C, NB);
    int s = 0;
    for (int i = lo; i < hi; i++) s += bhist[i];
    ssum[tid] = s;
    __syncthreads();
    for (int off = 1; off < 256; off <<= 1) {
        int v = (tid >= off) ? ssum[tid - off] : 0;
        __syncthreads();
        ssum[tid] += v;
        __syncthreads();
    }
    int run = (tid == 0) ? 0 : ssum[tid - 1];
    for (int i = lo; i < hi; i++) {
        bptr[i] = run;
        gcur[i] = run;
        run += bhist[i];
    }
    if (hi == NB) bptr[NB] = run;
}

// pass 3: reserve per-(block,bucket) ranges via one atomic each, then scatter
// through block-private LDS cursors. Each output region written by exactly one block.
__global__ __launch_bounds__(256) void radix_fill_kernel(
    const int* __restrict__ ei, const int* __restrict__ H, int* __restrict__ gcur,
    unsigned* __restrict__ ebuf, int E, int NB, int C) {
    __shared__ int lcur[MAXNB];
    int blk = blockIdx.x, tid = threadIdx.x;
    for (int i = tid; i < NB; i += 256) {
        int cntb = H[blk * NB + i];
        lcur[i] = cntb ? atomicAdd(&gcur[i], cntb) : 0;
    }
    __syncthreads();
    int lo = blk * C, hi = min(lo + C, E);
    for (int e = lo + tid; e < hi; e += 256) {
        int s = ei[e];
        int d = ei[E + e];
        int pos = atomicAdd(&lcur[d >> 6], 1);
        ebuf[pos] = ((unsigned)s << 6) | (unsigned)(d & 63);
    }
}

// per-bucket counting sort: ebuf bucket region -> node-sorted col; also row_ptr + dinv.
__global__ __launch_bounds__(256) void node_csr_kernel(
    const int* __restrict__ bptr, const unsigned* __restrict__ ebuf,
    int* __restrict__ row_ptr, int* __restrict__ col, float* __restrict__ dinv,
    int N, int NB) {
    __shared__ int lcnt[64];
    __shared__ int loff[64];
    __shared__ int lcur[64];
    int bkt = blockIdx.x, tid = threadIdx.x;
    int beg = bptr[bkt], end = bptr[bkt + 1];
    if (tid < 64) lcnt[tid] = 0;
    __syncthreads();
    for (int e = beg + tid; e < end; e += 256) atomicAdd(&lcnt[ebuf[e] & 63u], 1);
    __syncthreads();
    if (tid == 0) {
        int run = beg;
        for (int i = 0; i < 64; i++) { loff[i] = run; lcur[i] = run; run += lcnt[i]; }
    }
    __syncthreads();
    if (tid < 64) {
        int node = (bkt << 6) + tid;
        if (node < N) {
            row_ptr[node] = loff[tid];
            dinv[node] = rsqrtf((float)(lcnt[tid] + 1));  // +1 self loop
        }
    }
    if (tid == 0 && bkt == NB - 1) row_ptr[N] = end;
    for (int e = beg + tid; e < end; e += 256) {
        unsigned ev = ebuf[e];
        int pos = atomicAdd(&lcur[ev & 63u], 1);
        col[pos] = (int)(ev >> 6);
    }
}

// ================= g = bf16(dinv * (in @ W)) =================
// 16 nodes per block, 256 threads. In-place safe (block-local rows staged to LDS).
template <typename Tin, int K>
__global__ void gemm_g_kernel(const Tin* __restrict__ in,
                              const float* __restrict__ W,
                              const float* __restrict__ dinv,
                              unsigned short* __restrict__ g, int N) {
    __shared__ float sW[K * HID];
    __shared__ float sIn[16 * K];
    int tid = threadIdx.x;
    for (int idx = tid; idx < K * HID; idx += 256) sW[idx] = W[idx];
    int base = blockIdx.x * 16;
    for (int idx = tid; idx < 16 * K; idx += 256) {
        int r = idx / K, c = idx % K;
        int node = base + r;
        float v = 0.f;
        if (node < N) {
            Tin t = in[(long long)node * K + c];
            if constexpr (sizeof(Tin) == 2) v = bf2f((unsigned short)t);
            else v = (float)t;
        }
        sIn[idx] = v;
    }
    __syncthreads();
    int j = tid & 63;
    int si = tid >> 6;
#pragma unroll
    for (int u = 0; u < 4; u++) {
        int r = si * 4 + u;
        int node = base + r;
        if (node >= N) continue;
        float acc = 0.f;
#pragma unroll
        for (int k = 0; k < K; k++) acc += sIn[r * K + k] * sW[k * HID + j];
        g[(long long)node * HID + j] = f2bf(dinv[node] * acc);
    }
}

// ================= gather + combine: h[d] = relu(dinv[d]*(g[d] + sum_in g[s]) + b) ==========
// one wave per dst node, lane = feature; ILP-4 independent row loads.
__global__ __launch_bounds__(256) void gather_kernel(
    const int* __restrict__ row_ptr, const int* __restrict__ col,
    const unsigned short* __restrict__ g, const float* __restrict__ dinv,
    const float* __restrict__ bias, unsigned short* __restrict__ h, int N) {
    int node = blockIdx.x * 4 + (threadIdx.x >> 6);
    int lane = threadIdx.x & 63;
    if (node >= N) return;
    int beg = row_ptr[node], end = row_ptr[node + 1];
    float sum = bf2f(g[(long long)node * HID + lane]);  // self loop
    for (int e0 = beg; e0 < end; e0 += 64) {
        int myE = e0 + lane;
        int cs = (myE < end) ? col[myE] : 0;
        int cnt = min(64, end - e0);
        int j = 0;
        for (; j + 4 <= cnt; j += 4) {
            int s0 = __shfl(cs, j);
            int s1 = __shfl(cs, j + 1);
            int s2 = __shfl(cs, j + 2);
            int s3 = __shfl(cs, j + 3);
            float f0 = bf2f(g[(long long)s0 * HID + lane]);
            float f1 = bf2f(g[(long long)s1 * HID + lane]);
            float f2 = bf2f(g[(long long)s2 * HID + lane]);
            float f3 = bf2f(g[(long long)s3 * HID + lane]);
            sum += (f0 + f1) + (f2 + f3);
        }
        for (; j < cnt; j++) {
            int s = __shfl(cs, j);
            sum += bf2f(g[(long long)s * HID + lane]);
        }
    }
    float v = dinv[node] * sum + bias[lane];
    h[(long long)node * HID + lane] = f2bf(v > 0.f ? v : 0.f);
}

// ================= pooling: segmented reduction (batch is sorted) =================
__global__ void pool_kernel(const unsigned short* __restrict__ h, const int* __restrict__ batch,
                            float* __restrict__ sums, float* __restrict__ cnt, int N) {
    int wave = blockIdx.x * 4 + (threadIdx.x >> 6);
    int lane = threadIdx.x & 63;
    int lo = wave * 64;
    if (lo >= N) return;
    int hi = min(lo + 64, N);
    int curb = batch[lo];
    float sum = 0.f;
    int nseg = 0;
    for (int i = lo; i < hi; i++) {
        int b = batch[i];
        if (b != curb) {
            atomicAdd(&sums[curb * HID + lane], sum);
            if (lane == 0) atomicAdd(&cnt[curb], (float)nseg);
            curb = b; sum = 0.f; nseg = 0;
        }
        sum += bf2f(h[(long long)i * HID + lane]);
        nseg++;
    }
    atomicAdd(&sums[curb * HID + lane], sum);
    if (lane == 0) atomicAdd(&cnt[curb], (float)nseg);
}

// ================= final MLP head =================
__global__ void final_kernel(const float* __restrict__ sums, const float* __restrict__ cnt,
                             const float* __restrict__ Wf1, const float* __restrict__ bf1,
                             const float* __restrict__ Wf2, const float* __restrict__ bf2,
                             float* __restrict__ out) {
    __shared__ float sW1[HID * 32];
    __shared__ float sW2[32];
    int tid = threadIdx.x;
    for (int idx = tid; idx < HID * 32; idx += 128) sW1[idx] = Wf1[idx];
    if (tid < 32) sW2[tid] = Wf2[tid];
    __syncthreads();
    int b = tid;
    float pooled[HID];
    float c = fmaxf(cnt[b], 1.0f);
#pragma unroll
    for (int j = 0; j < HID; j++) pooled[j] = sums[b * HID + j] / c;
    float o = bf2[0];
#pragma unroll 4
    for (int hd = 0; hd < 32; hd++) {
        float z = bf1[hd];
#pragma unroll
        for (int j = 0; j < HID; j++) z += pooled[j] * sW1[j * 32 + hd];
        z = fmaxf(z, 0.f);
        o += z * sW2[hd];
    }
    out[b] = o;
}

extern "C" void kernel_launch(void* const* d_in, const int* in_sizes, int n_in,
                              void* d_out, int out_size, void* d_ws, size_t ws_size,
                              hipStream_t stream) {
    const float* x     = (const float*)d_in[0];
    const int*   ei    = (const int*)d_in[1];
    const int*   batch = (const int*)d_in[3];
    const float* W1  = (const float*)d_in[4];
    const float* b1  = (const float*)d_in[5];
    const float* W2  = (const float*)d_in[6];
    const float* b2  = (const float*)d_in[7];
    const float* W3  = (const float*)d_in[8];
    const float* b3  = (const float*)d_in[9];
    const float* Wf1 = (const float*)d_in[10];
    const float* bf1 = (const float*)d_in[11];
    const float* Wf2 = (const float*)d_in[12];
    const float* bf2 = (const float*)d_in[13];
    float* out = (float*)d_out;

    const int N  = in_sizes[0] / 16;   // 100000
    const int E  = in_sizes[1] / 2;    // 3200000
    const int NB = (N + 63) / 64;      // 1563 buckets

    // workspace layout (~55 MB)
    char* ws = (char*)d_ws;
    size_t o = 0;
    float*          dinv    = (float*)(ws + o);          o += ((size_t)N * 4 + 4095) / 4096 * 4096;
    int*            row_ptr = (int*)(ws + o);            o += ((size_t)(N + 1) * 4 + 4095) / 4096 * 4096;
    int*            bptr    = (int*)(ws + o);            o += ((size_t)(NB + 1) * 4 + 4095) / 4096 * 4096;
    int*            bhist   = (int*)(ws + o);            o += ((size_t)NB * 4 + 4095) / 4096 * 4096;
    int*            gcur    = (int*)(ws + o);            o += ((size_t)NB * 4 + 4095) / 4096 * 4096;
    int*            H       = (int*)(ws + o);            o += ((size_t)NBLK * NB * 4 + 4095) / 4096 * 4096;  // 0.8 MB
    unsigned*       ebuf    = (unsigned*)(ws + o);       o += (size_t)E * 4;        // 12.8 MB
    int*            col     = (int*)(ws + o);            o += (size_t)E * 4;        // 12.8 MB
    unsigned short* A       = (unsigned short*)(ws + o); o += (size_t)N * HID * 2;  // 12.8 MB
    unsigned short* B       = (unsigned short*)(ws + o); o += (size_t)N * HID * 2;  // 12.8 MB
    float*          sums    = (float*)(ws + o);          o += 128 * HID * 4;
    float*          cnt     = (float*)(ws + o);          o += 128 * 4;
    (void)ws_size;

    const int T = 256;
    const int Cchunk = (E + NBLK - 1) / NBLK;
    const int gGm = (N + 15) / 16;
    const int gGa = (N + 3) / 4;
    const int gPool = ((N + 63) / 64 + 3) / 4;

    // ---- CSR build: radix partition (reservation-based), then per-bucket counting sort ----
    hipMemsetAsync(bhist, 0, (size_t)NB * 4, stream);
    radix_hist_kernel<<<NBLK, T, 0, stream>>>(ei, H, bhist, E, NB, Cchunk);
    scan_kernel<<<1, T, 0, stream>>>(bhist, bptr, gcur, NB);
    radix_fill_kernel<<<NBLK, T, 0, stream>>>(ei, H, gcur, ebuf, E, NB, Cchunk);
    node_csr_kernel<<<NB, T, 0, stream>>>(bptr, ebuf, row_ptr, col, dinv, N, NB);

    // ---- layer 1: x(f32, K=16) -> A -> gather -> B ----
    gemm_g_kernel<float, 16><<<gGm, T, 0, stream>>>(x, W1, dinv, A, N);
    gather_kernel<<<gGa, T, 0, stream>>>(row_ptr, col, A, dinv, b1, B, N);

    // ---- layer 2: B -> B (in-place gemm) -> gather -> A ----
    gemm_g_kernel<unsigned short, 64><<<gGm, T, 0, stream>>>(B, W2, dinv, B, N);
    gather_kernel<<<gGa, T, 0, stream>>>(row_ptr, col, B, dinv, b2, A, N);

    // ---- layer 3: A -> A -> gather -> B ----
    gemm_g_kernel<unsigned short, 64><<<gGm, T, 0, stream>>>(A, W3, dinv, A, N);
    gather_kernel<<<gGa, T, 0, stream>>>(row_ptr, col, A, dinv, b3, B, N);

    // ---- pool + head ----
    hipMemsetAsync(sums, 0, (128 * HID + 128) * 4, stream);
    pool_kernel<<<gPool, T, 0, stream>>>(B, batch, sums, cnt, N);
    final_kernel<<<1, 128, 0, stream>>>(sums, cnt, Wf1, bf1, Wf2, bf2, out);
}

// Round 10
// 610.848 us; speedup vs baseline: 7.2380x; 1.0263x over previous
//
#include <hip/hip_runtime.h>
#include <hip/hip_bf16.h>

#define HID 64
#define MAXNB 2048   // max buckets (N <= 131072)
#define NBLK 128     // radix partition blocks
#define FILL_T 1024  // threads for hist/fill
#define SENT 0xFFFFFFFFu

__device__ __forceinline__ float bf2f(unsigned short u) {
    return __uint_as_float(((unsigned)u) << 16);
}
__device__ __forceinline__ unsigned short f2bf(float f) {
    __hip_bfloat16 b = __float2bfloat16(f);  // RNE
    return *(unsigned short*)&b;
}
__device__ __host__ __forceinline__ int ceil16(int c) { return (c + 15) & ~15; }

// ================= radix partition by bucket (bucket = dst >> 6) =================

// pass 1: per-block LDS histogram -> H[blk][NB], plus true + padded bucket totals
__global__ __launch_bounds__(FILL_T) void radix_hist_kernel(
    const int* __restrict__ ei, int* __restrict__ H, int* __restrict__ bhist,
    int* __restrict__ bhist_pad, int E, int NB, int C) {
    __shared__ int lh[MAXNB];
    int blk = blockIdx.x, tid = threadIdx.x;
    for (int i = tid; i < NB; i += FILL_T) lh[i] = 0;
    __syncthreads();
    int lo = blk * C, hi = min(lo + C, E);
    for (int e = lo + tid; e < hi; e += FILL_T) atomicAdd(&lh[ei[E + e] >> 6], 1);
    __syncthreads();
    for (int i = tid; i < NB; i += FILL_T) {
        int v = lh[i];
        H[blk * NB + i] = v;
        if (v) {
            atomicAdd(&bhist[i], v);
            atomicAdd(&bhist_pad[i], ceil16(v));
        }
    }
}

// pass 2: single-block scan over NB buckets: padded prefix (pptr, gcur) + compact prefix (cptr)
__global__ __launch_bounds__(256) void scan_kernel(
    const int* __restrict__ bhist, const int* __restrict__ bhist_pad,
    int* __restrict__ pptr, int* __restrict__ cptr, int* __restrict__ gcur, int NB) {
    __shared__ int ssum[256];
    __shared__ int psum[256];
    int tid = threadIdx.x;
    int C = (NB + 255) / 256;
    int lo = tid * C, hi = min(lo + C, NB);
    int s = 0, p = 0;
    for (int i = lo; i < hi; i++) { s += bhist[i]; p += bhist_pad[i]; }
    ssum[tid] = s; psum[tid] = p;
    __syncthreads();
    for (int off = 1; off < 256; off <<= 1) {
        int v = (tid >= off) ? ssum[tid - off] : 0;
        int w = (tid >= off) ? psum[tid - off] : 0;
        __syncthreads();
        ssum[tid] += v; psum[tid] += w;
        __syncthreads();
    }
    int runc = (tid == 0) ? 0 : ssum[tid - 1];
    int runp = (tid == 0) ? 0 : psum[tid - 1];
    for (int i = lo; i < hi; i++) {
        cptr[i] = runc;
        pptr[i] = runp;
        gcur[i] = runp;
        runc += bhist[i];
        runp += bhist_pad[i];
    }
    if (hi == NB) { cptr[NB] = runc; pptr[NB] = runp; }
}

// pass 3: reserve aligned per-(block,bucket) ranges, scatter via LDS cursors,
// sentinel-fill padding. Each 64B output line is written by exactly one block.
__global__ __launch_bounds__(FILL_T) void radix_fill_kernel(
    const int* __restrict__ ei, const int* __restrict__ H, int* __restrict__ gcur,
    unsigned* __restrict__ ebuf, int E, int NB, int C) {
    __shared__ int lcur[MAXNB];
    __shared__ int lend[MAXNB];
    int blk = blockIdx.x, tid = threadIdx.x;
    for (int i = tid; i < NB; i += FILL_T) {
        int cntb = H[blk * NB + i];
        int padc = ceil16(cntb);
        int start = padc ? atomicAdd(&gcur[i], padc) : 0;
        lcur[i] = start;
        lend[i] = start + padc;
    }
    __syncthreads();
    int lo = blk * C, hi = min(lo + C, E);
    for (int e = lo + tid; e < hi; e += FILL_T) {
        int s = ei[e];
        int d = ei[E + e];
        int pos = atomicAdd(&lcur[d >> 6], 1);
        ebuf[pos] = ((unsigned)s << 6) | (unsigned)(d & 63);
    }
    __syncthreads();
    // sentinel-fill pad tails (lcur now == region start + true count)
    for (int i = tid; i < NB; i += FILL_T) {
        for (int p = lcur[i]; p < lend[i]; p++) ebuf[p] = SENT;
    }
}

// per-bucket counting sort: padded ebuf region -> node-sorted compact col; row_ptr + dinv.
__global__ __launch_bounds__(256) void node_csr_kernel(
    const int* __restrict__ pptr, const int* __restrict__ cptr,
    const unsigned* __restrict__ ebuf,
    int* __restrict__ row_ptr, int* __restrict__ col, float* __restrict__ dinv,
    int N, int NB) {
    __shared__ int lcnt[64];
    __shared__ int loff[64];
    __shared__ int lcur[64];
    int bkt = blockIdx.x, tid = threadIdx.x;
    int beg = pptr[bkt], end = pptr[bkt + 1];
    int cbeg = cptr[bkt];
    if (tid < 64) lcnt[tid] = 0;
    __syncthreads();
    for (int e = beg + tid; e < end; e += 256) {
        unsigned ev = ebuf[e];
        if (ev != SENT) atomicAdd(&lcnt[ev & 63u], 1);
    }
    __syncthreads();
    if (tid == 0) {
        int run = cbeg;
        for (int i = 0; i < 64; i++) { loff[i] = run; lcur[i] = run; run += lcnt[i]; }
    }
    __syncthreads();
    if (tid < 64) {
        int node = (bkt << 6) + tid;
        if (node < N) {
            row_ptr[node] = loff[tid];
            dinv[node] = rsqrtf((float)(lcnt[tid] + 1));  // +1 self loop
        }
    }
    if (tid == 0 && bkt == NB - 1) row_ptr[N] = cptr[NB];
    for (int e = beg + tid; e < end; e += 256) {
        unsigned ev = ebuf[e];
        if (ev == SENT) continue;
        int pos = atomicAdd(&lcur[ev & 63u], 1);
        col[pos] = (int)(ev >> 6);
    }
}

// ================= g = bf16(dinv * (in @ W)) =================
template <typename Tin, int K>
__global__ void gemm_g_kernel(const Tin* __restrict__ in,
                              const float* __restrict__ W,
                              const float* __restrict__ dinv,
                              unsigned short* __restrict__ g, int N) {
    __shared__ float sW[K * HID];
    __shared__ float sIn[16 * K];
    int tid = threadIdx.x;
    for (int idx = tid; idx < K * HID; idx += 256) sW[idx] = W[idx];
    int base = blockIdx.x * 16;
    for (int idx = tid; idx < 16 * K; idx += 256) {
        int r = idx / K, c = idx % K;
        int node = base + r;
        float v = 0.f;
        if (node < N) {
            Tin t = in[(long long)node * K + c];
            if constexpr (sizeof(Tin) == 2) v = bf2f((unsigned short)t);
            else v = (float)t;
        }
        sIn[idx] = v;
    }
    __syncthreads();
    int j = tid & 63;
    int si = tid >> 6;
#pragma unroll
    for (int u = 0; u < 4; u++) {
        int r = si * 4 + u;
        int node = base + r;
        if (node >= N) continue;
        float acc = 0.f;
#pragma unroll
        for (int k = 0; k < K; k++) acc += sIn[r * K + k] * sW[k * HID + j];
        g[(long long)node * HID + j] = f2bf(dinv[node] * acc);
    }
}

// ================= gather + combine: h[d] = relu(dinv[d]*(g[d] + sum_in g[s]) + b) ==========
__global__ __launch_bounds__(256) void gather_kernel(
    const int* __restrict__ row_ptr, const int* __restrict__ col,
    const unsigned short* __restrict__ g, const float* __restrict__ dinv,
    const float* __restrict__ bias, unsigned short* __restrict__ h, int N) {
    int node = blockIdx.x * 4 + (threadIdx.x >> 6);
    int lane = threadIdx.x & 63;
    if (node >= N) return;
    int beg = row_ptr[node], end = row_ptr[node + 1];
    float sum = bf2f(g[(long long)node * HID + lane]);  // self loop
    for (int e0 = beg; e0 < end; e0 += 64) {
        int myE = e0 + lane;
        int cs = (myE < end) ? col[myE] : 0;
        int cnt = min(64, end - e0);
        int j = 0;
        for (; j + 4 <= cnt; j += 4) {
            int s0 = __shfl(cs, j);
            int s1 = __shfl(cs, j + 1);
            int s2 = __shfl(cs, j + 2);
            int s3 = __shfl(cs, j + 3);
            float f0 = bf2f(g[(long long)s0 * HID + lane]);
            float f1 = bf2f(g[(long long)s1 * HID + lane]);
            float f2 = bf2f(g[(long long)s2 * HID + lane]);
            float f3 = bf2f(g[(long long)s3 * HID + lane]);
            sum += (f0 + f1) + (f2 + f3);
        }
        for (; j < cnt; j++) {
            int s = __shfl(cs, j);
            sum += bf2f(g[(long long)s * HID + lane]);
        }
    }
    float v = dinv[node] * sum + bias[lane];
    h[(long long)node * HID + lane] = f2bf(v > 0.f ? v : 0.f);
}

// ================= pooling: segmented reduction (batch is sorted) =================
__global__ void pool_kernel(const unsigned short* __restrict__ h, const int* __restrict__ batch,
                            float* __restrict__ sums, float* __restrict__ cnt, int N) {
    int wave = blockIdx.x * 4 + (threadIdx.x >> 6);
    int lane = threadIdx.x & 63;
    int lo = wave * 64;
    if (lo >= N) return;
    int hi = min(lo + 64, N);
    int curb = batch[lo];
    float sum = 0.f;
    int nseg = 0;
    for (int i = lo; i < hi; i++) {
        int b = batch[i];
        if (b != curb) {
            atomicAdd(&sums[curb * HID + lane], sum);
            if (lane == 0) atomicAdd(&cnt[curb], (float)nseg);
            curb = b; sum = 0.f; nseg = 0;
        }
        sum += bf2f(h[(long long)i * HID + lane]);
        nseg++;
    }
    atomicAdd(&sums[curb * HID + lane], sum);
    if (lane == 0) atomicAdd(&cnt[curb], (float)nseg);
}

// ================= final MLP head =================
__global__ void final_kernel(const float* __restrict__ sums, const float* __restrict__ cnt,
                             const float* __restrict__ Wf1, const float* __restrict__ bf1,
                             const float* __restrict__ Wf2, const float* __restrict__ bf2,
                             float* __restrict__ out) {
    __shared__ float sW1[HID * 32];
    __shared__ float sW2[32];
    int tid = threadIdx.x;
    for (int idx = tid; idx < HID * 32; idx += 128) sW1[idx] = Wf1[idx];
    if (tid < 32) sW2[tid] = Wf2[tid];
    __syncthreads();
    int b = tid;
    float pooled[HID];
    float c = fmaxf(cnt[b], 1.0f);
#pragma unroll
    for (int j = 0; j < HID; j++) pooled[j] = sums[b * HID + j] / c;
    float o = bf2[0];
#pragma unroll 4
    for (int hd = 0; hd < 32; hd++) {
        float z = bf1[hd];
#pragma unroll
        for (int j = 0; j < HID; j++) z += pooled[j] * sW1[j * 32 + hd];
        z = fmaxf(z, 0.f);
        o += z * sW2[hd];
    }
    out[b] = o;
}

extern "C" void kernel_launch(void* const* d_in, const int* in_sizes, int n_in,
                              void* d_out, int out_size, void* d_ws, size_t ws_size,
                              hipStream_t stream) {
    const float* x     = (const float*)d_in[0];
    const int*   ei    = (const int*)d_in[1];
    const int*   batch = (const int*)d_in[3];
    const float* W1  = (const float*)d_in[4];
    const float* b1  = (const float*)d_in[5];
    const float* W2  = (const float*)d_in[6];
    const float* b2  = (const float*)d_in[7];
    const float* W3  = (const float*)d_in[8];
    const float* b3  = (const float*)d_in[9];
    const float* Wf1 = (const float*)d_in[10];
    const float* bf1 = (const float*)d_in[11];
    const float* Wf2 = (const float*)d_in[12];
    const float* bf2 = (const float*)d_in[13];
    float* out = (float*)d_out;

    const int N  = in_sizes[0] / 16;   // 100000
    const int E  = in_sizes[1] / 2;    // 3200000
    const int NB = (N + 63) / 64;      // 1563 buckets
    // padded ebuf worst case: E + NBLK*NB*15; typical E + NBLK*NB*8 (~19 MB)
    const size_t EBUF_CAP = (size_t)E + (size_t)NBLK * NB * 15;

    // workspace layout (~62 MB)
    char* ws = (char*)d_ws;
    size_t o = 0;
    float*          dinv    = (float*)(ws + o);          o += ((size_t)N * 4 + 4095) / 4096 * 4096;
    int*            row_ptr = (int*)(ws + o);            o += ((size_t)(N + 1) * 4 + 4095) / 4096 * 4096;
    int*            pptr    = (int*)(ws + o);            o += ((size_t)(NB + 1) * 4 + 4095) / 4096 * 4096;
    int*            cptr    = (int*)(ws + o);            o += ((size_t)(NB + 1) * 4 + 4095) / 4096 * 4096;
    int*            bhist   = (int*)(ws + o);            o += ((size_t)(2 * NB) * 4 + 4095) / 4096 * 4096;
    int*            bhist_pad = bhist + NB;
    int*            gcur    = (int*)(ws + o);            o += ((size_t)NB * 4 + 4095) / 4096 * 4096;
    int*            H       = (int*)(ws + o);            o += ((size_t)NBLK * NB * 4 + 4095) / 4096 * 4096;  // 0.8 MB
    unsigned*       ebuf    = (unsigned*)(ws + o);       o += EBUF_CAP * 4;         // ~25 MB cap
    int*            col     = (int*)(ws + o);            o += (size_t)E * 4;        // 12.8 MB
    unsigned short* A       = (unsigned short*)(ws + o); o += (size_t)N * HID * 2;  // 12.8 MB
    unsigned short* B       = (unsigned short*)(ws + o); o += (size_t)N * HID * 2;  // 12.8 MB
    float*          sums    = (float*)(ws + o);          o += 128 * HID * 4;
    float*          cnt     = (float*)(ws + o);          o += 128 * 4;
    (void)ws_size;

    const int T = 256;
    const int Cchunk = (E + NBLK - 1) / NBLK;
    const int gGm = (N + 15) / 16;
    const int gGa = (N + 3) / 4;
    const int gPool = ((N + 63) / 64 + 3) / 4;

    // ---- CSR build: aligned radix partition, then per-bucket counting sort ----
    hipMemsetAsync(bhist, 0, (size_t)(2 * NB) * 4, stream);
    radix_hist_kernel<<<NBLK, FILL_T, 0, stream>>>(ei, H, bhist, bhist_pad, E, NB, Cchunk);
    scan_kernel<<<1, T, 0, stream>>>(bhist, bhist_pad, pptr, cptr, gcur, NB);
    radix_fill_kernel<<<NBLK, FILL_T, 0, stream>>>(ei, H, gcur, ebuf, E, NB, Cchunk);
    node_csr_kernel<<<NB, T, 0, stream>>>(pptr, cptr, ebuf, row_ptr, col, dinv, N, NB);

    // ---- layer 1: x(f32, K=16) -> A -> gather -> B ----
    gemm_g_kernel<float, 16><<<gGm, T, 0, stream>>>(x, W1, dinv, A, N);
    gather_kernel<<<gGa, T, 0, stream>>>(row_ptr, col, A, dinv, b1, B, N);

    // ---- layer 2: B -> B (in-place gemm) -> gather -> A ----
    gemm_g_kernel<unsigned short, 64><<<gGm, T, 0, stream>>>(B, W2, dinv, B, N);
    gather_kernel<<<gGa, T, 0, stream>>>(row_ptr, col, B, dinv, b2, A, N);

    // ---- layer 3: A -> A -> gather -> B ----
    gemm_g_kernel<unsigned short, 64><<<gGm, T, 0, stream>>>(A, W3, dinv, A, N);
    gather_kernel<<<gGa, T, 0, stream>>>(row_ptr, col, A, dinv, b3, B, N);

    // ---- pool + head ----
    hipMemsetAsync(sums, 0, (128 * HID + 128) * 4, stream);
    pool_kernel<<<gPool, T, 0, stream>>>(B, batch, sums, cnt, N);
    final_kernel<<<1, 128, 0, stream>>>(sums, cnt, Wf1, bf1, Wf2, bf2, out);
}